// Round 10
// baseline (146.568 us; speedup 1.0000x reference)
//
#include <hip/hip_runtime.h>
#include <hip/hip_bf16.h>
#include <stdint.h>

// SparseSwiGLU on MI355X: fine-band radix densify -> bf16 weights -> MFMA GEMMs.
// R10: revert to R8 256-band binning; fuse build(WDOWN) blocks into the
// gemm_upgate launch (heterogeneous roles, interleaved b%3) for overlap.
// T=512 tokens, DIM=1024, HIDDEN=4096, NNZ=262144 per matrix.
//
// Workspace layout (<= 67 MB):
//   [0,    8MB)  WUP    bf16 [4096][1024]   (B^T, K-contiguous)
//   [8MB, 16MB)  WGATE  bf16 [4096][1024]
//   [16MB,24MB)  WDOWN  bf16 [1024][4096]
//   [24MB,25MB)  XB     bf16 [512][1024]
//   [25MB,29MB)  HID    bf16 [512][4096]
//   [29MB,+36MB) BANDS  uint2[3][256 band][256 chunk][24 slot]
//   [66MB,+768K) CNT    int[3][256][256]

#define DIM_    1024
#define HIDDEN_ 4096
#define NNZ_    262144
#define TTOK_   512
#define PAD_    24              // 192 B segments, single-writer

typedef __attribute__((ext_vector_type(8))) short short8;
typedef __attribute__((ext_vector_type(4))) float float4v;

__device__ inline unsigned short f2bf(float f) {
    union { float f; unsigned int u; } c; c.f = f;
    unsigned int u = c.u;
    unsigned int r = u + 0x7fffu + ((u >> 16) & 1u);   // RNE
    return (unsigned short)(r >> 16);
}

__device__ inline void async16(const unsigned short* g, unsigned short* l) {
    __builtin_amdgcn_global_load_lds(
        (const __attribute__((address_space(1))) unsigned int*)g,
        (__attribute__((address_space(3))) unsigned int*)l, 16, 0, 0);
}

// ---------------------------------------------------------------- bin+prep (R8)
// Blocks [0,768): bin — block = (mat, chunk of 1024 nnz), 256 bands/mat
//   (16 rows up/gate, 4 down). Entry (rrel<<12|col, valbits) into the block's
//   own 192B segment per band; counts -> CNT. Poisson(4)/bin, P(>24)~1e-11.
// Blocks [768,1024): prep — x->bf16 and out = x + down_bias (4 float4/thr).
#define XC_ ((TTOK_ * DIM_) / 4)           // 131072 float4 units

__global__ __launch_bounds__(256) void bin_prep_kernel(
    const int* __restrict__ ur, const int* __restrict__ uc, const float* __restrict__ uv,
    const int* __restrict__ gr, const int* __restrict__ gc, const float* __restrict__ gv,
    const int* __restrict__ dr, const int* __restrict__ dc, const float* __restrict__ dv,
    const float* __restrict__ x, const float* __restrict__ down_bias,
    uint2* __restrict__ bands, int* __restrict__ cnt,
    unsigned short* __restrict__ xb, float* __restrict__ out) {
    const int b = blockIdx.x;
    const int t = threadIdx.x;
    if (b >= 768) {
        const unsigned int u0 = (b - 768) * 1024 + t * 4;
        #pragma unroll
        for (int q = 0; q < 4; ++q) {
            const unsigned int id = u0 + q;
            if (id < XC_) {
                float4 v = ((const float4*)x)[id];
                ushort4 o;
                o.x = f2bf(v.x); o.y = f2bf(v.y); o.z = f2bf(v.z); o.w = f2bf(v.w);
                ((ushort4*)xb)[id] = o;
            } else {
                const unsigned int i = id - XC_;
                float4 v = ((const float4*)x)[i];
                const int d = (i * 4) & (DIM_ - 1);
                const float4 bb = *(const float4*)(down_bias + d);
                float4 o;
                o.x = v.x + bb.x; o.y = v.y + bb.y; o.z = v.z + bb.z; o.w = v.w + bb.w;
                ((float4*)out)[i] = o;
            }
        }
        return;
    }
    __shared__ int lcount[256];
    const int mat = b >> 8;          // 0 up, 1 gate, 2 down
    const int chunk = b & 255;
    const int*   rs = (mat == 0) ? ur : (mat == 1) ? gr : dr;
    const int*   cs = (mat == 0) ? uc : (mat == 1) ? gc : dc;
    const float* vs = (mat == 0) ? uv : (mat == 1) ? gv : dv;
    const int shift = (mat == 2) ? 2 : 4;   // rows/band: 4 (down), 16 (up/gate)
    const int rmask = (mat == 2) ? 3 : 15;
    lcount[t] = 0;
    __syncthreads();

    const int base = chunk * 1024 + t * 4;
    int4   r4 = *(const int4*)(rs + base);
    int4   c4 = *(const int4*)(cs + base);
    float4 v4 = *(const float4*)(vs + base);
    uint2* mbase = bands + mat * (256 * 256 * PAD_);
    int   rr[4] = {r4.x, r4.y, r4.z, r4.w};
    int   cc[4] = {c4.x, c4.y, c4.z, c4.w};
    float vv[4] = {v4.x, v4.y, v4.z, v4.w};
    #pragma unroll
    for (int j = 0; j < 4; ++j) {
        const int band = rr[j] >> shift;
        const int pos = atomicAdd(&lcount[band], 1);
        if (pos < PAD_) {
            uint2 e;
            e.x = ((unsigned int)(rr[j] & rmask) << 12) | (unsigned int)cc[j];
            e.y = __float_as_uint(vv[j]);
            mbase[(band * 256 + chunk) * PAD_ + pos] = e;
        }
    }
    __syncthreads();
    cnt[(mat * 256 + t) * 256 + chunk] = lcount[t];
}

// ---------------------------------------------------------------- build up/gate
// R8 build restricted to mats 0,1: 512 blocks x 512 thr, one band (16 rows,
// 64KB fp32 LDS) per block. Half 0 loads slots 0..11 unconditionally.
__global__ __launch_bounds__(512) void build_upgate_kernel(
    const uint2* __restrict__ bands,
    const int* __restrict__ cnt,
    unsigned short* __restrict__ WUP,
    unsigned short* __restrict__ WGATE) {
    __shared__ float acc[16 * 1024];
    __shared__ int lcnt[256];
    const int b = blockIdx.x;
    const int t = threadIdx.x;
    const int mat = b >> 8;          // 0 or 1
    const int band = b & 255;
    unsigned short* out = (mat == 0 ? WUP : WGATE) + band * 16 * 1024;

    for (int k = 0; k < 8; ++k)
        *(float4*)&acc[(k * 512 + t) * 4] = make_float4(0.f, 0.f, 0.f, 0.f);
    if (t < 256) lcnt[t] = cnt[(mat * 256 + band) * 256 + t];
    __syncthreads();

    const int chunk = t & 255;
    const int half = t >> 8;
    const uint2* seg = bands + (((mat * 256 + band) * 256) + chunk) * PAD_;
    const int c = lcnt[chunk];

    if (half == 0) {
        uint4 q[6];
        const uint4* sp = (const uint4*)seg;
        #pragma unroll
        for (int i = 0; i < 6; ++i) q[i] = sp[i];
        #pragma unroll
        for (int j = 0; j < 12; ++j) {
            const unsigned int ex = (j & 1) ? q[j >> 1].z : q[j >> 1].x;
            const unsigned int ey = (j & 1) ? q[j >> 1].w : q[j >> 1].y;
            if (j < c)
                atomicAdd(&acc[(ex >> 12) * 1024 + (ex & 0xFFFu)],
                          __uint_as_float(ey));
        }
    } else {
        for (int j = 12; j < c && j < PAD_; ++j) {
            uint2 e = seg[j];
            atomicAdd(&acc[(e.x >> 12) * 1024 + (e.x & 0xFFFu)],
                      __uint_as_float(e.y));
        }
    }
    __syncthreads();

    for (int k = 0; k < 8; ++k) {
        const int cc = (k * 512 + t) * 4;
        ushort4 o;
        o.x = f2bf(acc[cc]);     o.y = f2bf(acc[cc + 1]);
        o.z = f2bf(acc[cc + 2]); o.w = f2bf(acc[cc + 3]);
        *(ushort4*)(out + cc) = o;
    }
}

// ---------------------------------------------------------------- fused
// 768 blocks x 256 thr, interleaved roles: b%3==2 -> build WDOWN band b/3
// (4 rows, 64KB fp32 LDS, 1 thread per chunk); else gemm_upgate block
// gidx=(b/3)*2+(b%3) (tile 64Mx64N, BK=64, dual acc). Roles co-resident per
// CU so build_down hides inside gemm stalls. LDS = union (65KB static).
__global__ __launch_bounds__(256) void fused_upgate_builddown_kernel(
    const unsigned short* __restrict__ xb,      // [512][1024]
    const unsigned short* __restrict__ wup,     // [4096][1024]
    const unsigned short* __restrict__ wgate,   // [4096][1024]
    const float* __restrict__ up_bias,
    const float* __restrict__ gate_bias,
    unsigned short* __restrict__ hid,           // [512][4096]
    const uint2* __restrict__ bands,
    const int* __restrict__ cnt,
    unsigned short* __restrict__ WDOWN) {
    __shared__ __align__(16) unsigned char smem[66560];   // 64KB acc + 1KB lcnt | 24KB gemm tiles
    const int b = blockIdx.x;
    const int t = threadIdx.x;

    if (b % 3 == 2) {
        // ---------------- build WDOWN band (4 rows x 4096)
        float* acc = (float*)smem;                 // 16384 floats
        int* lcnt = (int*)(smem + 65536);
        const int band = b / 3;
        for (int k = 0; k < 16; ++k)
            *(float4*)&acc[(k * 256 + t) * 4] = make_float4(0.f, 0.f, 0.f, 0.f);
        lcnt[t] = cnt[(2 * 256 + band) * 256 + t];
        __syncthreads();

        const uint2* seg = bands + (((2 * 256 + band) * 256) + t) * PAD_;
        const int c = lcnt[t];
        uint4 q[6];
        const uint4* sp = (const uint4*)seg;
        #pragma unroll
        for (int i = 0; i < 6; ++i) q[i] = sp[i];
        #pragma unroll
        for (int j = 0; j < 12; ++j) {
            const unsigned int ex = (j & 1) ? q[j >> 1].z : q[j >> 1].x;
            const unsigned int ey = (j & 1) ? q[j >> 1].w : q[j >> 1].y;
            if (j < c)
                atomicAdd(&acc[(ex >> 12) * 4096 + (ex & 0xFFFu)],
                          __uint_as_float(ey));
        }
        for (int j = 12; j < c && j < PAD_; ++j) {   // rare tail
            uint2 e = seg[j];
            atomicAdd(&acc[(e.x >> 12) * 4096 + (e.x & 0xFFFu)],
                      __uint_as_float(e.y));
        }
        __syncthreads();

        unsigned short* out = WDOWN + band * 4 * 4096;
        for (int k = 0; k < 16; ++k) {
            const int cc = (k * 256 + t) * 4;
            ushort4 o;
            o.x = f2bf(acc[cc]);     o.y = f2bf(acc[cc + 1]);
            o.z = f2bf(acc[cc + 2]); o.w = f2bf(acc[cc + 3]);
            *(ushort4*)(out + cc) = o;
        }
        return;
    }

    // ---------------- gemm_upgate block
    unsigned short* sA  = (unsigned short*)smem;         // 2*64*32 = 8KB
    unsigned short* sBu = sA + 4096;
    unsigned short* sBg = sBu + 4096;
    const int gidx = (b / 3) * 2 + (b % 3);              // 0..511
    const int n0 = (gidx & 63) * 64;
    const int m0 = (gidx >> 6) * 64;
    const int w = t >> 6, l = t & 63;
    const int wm = (w >> 1) * 32, wn = (w & 1) * 32;
    const int lr = l & 15, lkq = (l >> 4);

    float4v au[2][2], ag[2][2];
    for (int im = 0; im < 2; ++im)
        for (int in = 0; in < 2; ++in) {
            au[im][in] = float4v{0.f, 0.f, 0.f, 0.f};
            ag[im][in] = float4v{0.f, 0.f, 0.f, 0.f};
        }

    const int srow = t >> 2, scol = (t & 3) * 8;
    const unsigned short* gA  = xb    + (m0 + srow) * DIM_ + scol;
    const unsigned short* gBu = wup   + (n0 + srow) * DIM_ + scol;
    const unsigned short* gBg = wgate + (n0 + srow) * DIM_ + scol;

    for (int k0 = 0; k0 < DIM_; k0 += 64) {
        async16(gA + k0,       &sA[t * 8]);
        async16(gA + k0 + 32,  &sA[2048 + t * 8]);
        async16(gBu + k0,      &sBu[t * 8]);
        async16(gBu + k0 + 32, &sBu[2048 + t * 8]);
        async16(gBg + k0,      &sBg[t * 8]);
        async16(gBg + k0 + 32, &sBg[2048 + t * 8]);
        __syncthreads();
        #pragma unroll
        for (int kk = 0; kk < 2; ++kk) {
            const int kb = kk * 2048 + lkq * 8;
            short8 a[2], bu[2], bg[2];
            for (int im = 0; im < 2; ++im)
                a[im] = *(const short8*)&sA[kb + (wm + im * 16 + lr) * 32];
            for (int in = 0; in < 2; ++in) {
                bu[in] = *(const short8*)&sBu[kb + (wn + in * 16 + lr) * 32];
                bg[in] = *(const short8*)&sBg[kb + (wn + in * 16 + lr) * 32];
            }
            for (int im = 0; im < 2; ++im)
                for (int in = 0; in < 2; ++in) {
                    au[im][in] = __builtin_amdgcn_mfma_f32_16x16x32_bf16(
                        a[im], bu[in], au[im][in], 0, 0, 0);
                    ag[im][in] = __builtin_amdgcn_mfma_f32_16x16x32_bf16(
                        a[im], bg[in], ag[im][in], 0, 0, 0);
                }
        }
        __syncthreads();
    }

    for (int im = 0; im < 2; ++im) {
        for (int in = 0; in < 2; ++in) {
            const int n = n0 + wn + in * 16 + lr;
            const float ub = up_bias[n], gb = gate_bias[n];
            for (int r = 0; r < 4; ++r) {
                const int m = m0 + wm + im * 16 + lkq * 4 + r;
                const float u = au[im][in][r] + ub;
                const float g = ag[im][in][r] + gb;
                const float h = (u / (1.f + __expf(-u))) * g;
                hid[m * HIDDEN_ + n] = f2bf(h);
            }
        }
    }
}

// ---------------------------------------------------------------- down GEMM (R8)
// BK=64, split-K=8 (grid 1024 = 4 blocks/CU). atomicAdd epilogue onto
// d_out (pre-initialized to x + down_bias by prep role of bin_prep).
__global__ __launch_bounds__(256) void gemm_down_kernel(
    const unsigned short* __restrict__ hid,     // [512][4096]
    const unsigned short* __restrict__ wdown,   // [1024][4096]
    float* __restrict__ out) {                  // [512][1024]
    __shared__ unsigned short sA[2 * 64 * 32];
    __shared__ unsigned short sB[2 * 64 * 32];
    const int t = threadIdx.x;
    const int n0 = blockIdx.x * 64;
    const int m0 = blockIdx.y * 64;
    const int kb0 = blockIdx.z * 512;
    const int w = t >> 6, l = t & 63;
    const int wm = (w >> 1) * 32, wn = (w & 1) * 32;
    const int lr = l & 15, lkq = (l >> 4);

    float4v acc[2][2];
    for (int im = 0; im < 2; ++im)
        for (int in = 0; in < 2; ++in)
            acc[im][in] = float4v{0.f, 0.f, 0.f, 0.f};

    const int srow = t >> 2, scol = (t & 3) * 8;
    const unsigned short* gA = hid   + (m0 + srow) * HIDDEN_ + scol;
    const unsigned short* gB = wdown + (n0 + srow) * HIDDEN_ + scol;

    for (int k0 = kb0; k0 < kb0 + 512; k0 += 64) {
        async16(gA + k0,      &sA[t * 8]);
        async16(gA + k0 + 32, &sA[2048 + t * 8]);
        async16(gB + k0,      &sB[t * 8]);
        async16(gB + k0 + 32, &sB[2048 + t * 8]);
        __syncthreads();
        #pragma unroll
        for (int kk = 0; kk < 2; ++kk) {
            const int kb = kk * 2048 + lkq * 8;
            short8 a[2], b[2];
            for (int im = 0; im < 2; ++im)
                a[im] = *(const short8*)&sA[kb + (wm + im * 16 + lr) * 32];
            for (int in = 0; in < 2; ++in)
                b[in] = *(const short8*)&sB[kb + (wn + in * 16 + lr) * 32];
            for (int im = 0; im < 2; ++im)
                for (int in = 0; in < 2; ++in)
                    acc[im][in] = __builtin_amdgcn_mfma_f32_16x16x32_bf16(
                        a[im], b[in], acc[im][in], 0, 0, 0);
        }
        __syncthreads();
    }

    for (int im = 0; im < 2; ++im) {
        for (int in = 0; in < 2; ++in) {
            const int n = n0 + wn + in * 16 + lr;
            for (int r = 0; r < 4; ++r) {
                const int m = m0 + wm + im * 16 + lkq * 4 + r;
                atomicAdd(out + m * DIM_ + n, acc[im][in][r]);
            }
        }
    }
}

// ---------------------------------------------------------------- launch
extern "C" void kernel_launch(void* const* d_in, const int* in_sizes, int n_in,
                              void* d_out, int out_size, void* d_ws, size_t ws_size,
                              hipStream_t stream) {
    const float* x         = (const float*)d_in[0];
    const int*   up_row    = (const int*)d_in[1];
    const int*   up_col    = (const int*)d_in[2];
    const float* up_val    = (const float*)d_in[3];
    const float* up_bias   = (const float*)d_in[4];
    const int*   gate_row  = (const int*)d_in[5];
    const int*   gate_col  = (const int*)d_in[6];
    const float* gate_val  = (const float*)d_in[7];
    const float* gate_bias = (const float*)d_in[8];
    const int*   down_row  = (const int*)d_in[9];
    const int*   down_col  = (const int*)d_in[10];
    const float* down_val  = (const float*)d_in[11];
    const float* down_bias = (const float*)d_in[12];
    float* out = (float*)d_out;

    unsigned char* ws = (unsigned char*)d_ws;
    unsigned short* WUP   = (unsigned short*)(ws);
    unsigned short* WGATE = (unsigned short*)(ws + (8u << 20));
    unsigned short* WDOWN = (unsigned short*)(ws + (16u << 20));
    unsigned short* XB    = (unsigned short*)(ws + (24u << 20));
    unsigned short* HID   = (unsigned short*)(ws + (25u << 20));
    uint2*          BANDS = (uint2*)(ws + (29u << 20));
    int*            CNT   = (int*)(ws + (66u << 20));

    bin_prep_kernel<<<1024, 256, 0, stream>>>(
        up_row, up_col, up_val, gate_row, gate_col, gate_val,
        down_row, down_col, down_val, x, down_bias, BANDS, CNT, XB, out);

    build_upgate_kernel<<<512, 512, 0, stream>>>(BANDS, CNT, WUP, WGATE);

    fused_upgate_builddown_kernel<<<768, 256, 0, stream>>>(
        XB, WUP, WGATE, up_bias, gate_bias, HID, BANDS, CNT, WDOWN);

    gemm_down_kernel<<<dim3(DIM_ / 64, TTOK_ / 64, 8), 256, 0, stream>>>(
        HID, WDOWN, out);
}

// Round 11
// 139.495 us; speedup vs baseline: 1.0507x; 1.0507x over previous
//
#include <hip/hip_runtime.h>
#include <hip/hip_bf16.h>
#include <stdint.h>

// SparseSwiGLU on MI355X: fine-band radix densify -> bf16 weights -> MFMA GEMMs.
// R11 = R8 (best, 138.3us) + 4-byte bin entries ((rrel<<28)|(col<<16)|bf16val):
// 128B single-writer segments, 64B unconditional build loads, ~40% less
// densify traffic. T=512 tokens, DIM=1024, HIDDEN=4096, NNZ=262144/matrix.
//
// Workspace layout (<= 67 MB):
//   [0,    8MB)  WUP    bf16 [4096][1024]   (B^T, K-contiguous)
//   [8MB, 16MB)  WGATE  bf16 [4096][1024]
//   [16MB,24MB)  WDOWN  bf16 [1024][4096]
//   [24MB,25MB)  XB     bf16 [512][1024]
//   [25MB,29MB)  HID    bf16 [512][4096]
//   [29MB,+25MB) BANDS  uint[3][256 band][256 chunk][32 slot]
//   [66MB,+768K) CNT    int[3][256][256]

#define DIM_    1024
#define HIDDEN_ 4096
#define NNZ_    262144
#define TTOK_   512
#define PAD_    32              // 128 B segments (2 lines), single-writer

typedef __attribute__((ext_vector_type(8))) short short8;
typedef __attribute__((ext_vector_type(4))) float float4v;

__device__ inline unsigned short f2bf(float f) {
    union { float f; unsigned int u; } c; c.f = f;
    unsigned int u = c.u;
    unsigned int r = u + 0x7fffu + ((u >> 16) & 1u);   // RNE
    return (unsigned short)(r >> 16);
}

__device__ inline void async16(const unsigned short* g, unsigned short* l) {
    __builtin_amdgcn_global_load_lds(
        (const __attribute__((address_space(1))) unsigned int*)g,
        (__attribute__((address_space(3))) unsigned int*)l, 16, 0, 0);
}

// ---------------------------------------------------------------- bin+prep
// Blocks [0,768): bin — block = (mat, chunk of 1024 nnz), 256 bands/mat
//   (16 rows up/gate, 4 down). Entry (rrel<<28|col<<16|bf16val) into the
//   block's own 128B segment per band; counts -> CNT. Poisson(4)/bin.
// Blocks [768,1024): prep — x->bf16 and out = x + down_bias (4 float4/thr).
#define XC_ ((TTOK_ * DIM_) / 4)           // 131072 float4 units

__global__ __launch_bounds__(256) void bin_prep_kernel(
    const int* __restrict__ ur, const int* __restrict__ uc, const float* __restrict__ uv,
    const int* __restrict__ gr, const int* __restrict__ gc, const float* __restrict__ gv,
    const int* __restrict__ dr, const int* __restrict__ dc, const float* __restrict__ dv,
    const float* __restrict__ x, const float* __restrict__ down_bias,
    unsigned int* __restrict__ bands, int* __restrict__ cnt,
    unsigned short* __restrict__ xb, float* __restrict__ out) {
    const int b = blockIdx.x;
    const int t = threadIdx.x;
    if (b >= 768) {
        const unsigned int u0 = (b - 768) * 1024 + t * 4;
        #pragma unroll
        for (int q = 0; q < 4; ++q) {
            const unsigned int id = u0 + q;
            if (id < XC_) {
                float4 v = ((const float4*)x)[id];
                ushort4 o;
                o.x = f2bf(v.x); o.y = f2bf(v.y); o.z = f2bf(v.z); o.w = f2bf(v.w);
                ((ushort4*)xb)[id] = o;
            } else {
                const unsigned int i = id - XC_;
                float4 v = ((const float4*)x)[i];
                const int d = (i * 4) & (DIM_ - 1);
                const float4 bb = *(const float4*)(down_bias + d);
                float4 o;
                o.x = v.x + bb.x; o.y = v.y + bb.y; o.z = v.z + bb.z; o.w = v.w + bb.w;
                ((float4*)out)[i] = o;
            }
        }
        return;
    }
    __shared__ int lcount[256];
    const int mat = b >> 8;          // 0 up, 1 gate, 2 down
    const int chunk = b & 255;
    const int*   rs = (mat == 0) ? ur : (mat == 1) ? gr : dr;
    const int*   cs = (mat == 0) ? uc : (mat == 1) ? gc : dc;
    const float* vs = (mat == 0) ? uv : (mat == 1) ? gv : dv;
    const int shift = (mat == 2) ? 2 : 4;   // rows/band: 4 (down), 16 (up/gate)
    const int rmask = (mat == 2) ? 3 : 15;
    lcount[t] = 0;
    __syncthreads();

    const int base = chunk * 1024 + t * 4;
    int4   r4 = *(const int4*)(rs + base);
    int4   c4 = *(const int4*)(cs + base);
    float4 v4 = *(const float4*)(vs + base);
    unsigned int* mbase = bands + mat * (256 * 256 * PAD_);
    int   rr[4] = {r4.x, r4.y, r4.z, r4.w};
    int   cc[4] = {c4.x, c4.y, c4.z, c4.w};
    float vv[4] = {v4.x, v4.y, v4.z, v4.w};
    #pragma unroll
    for (int j = 0; j < 4; ++j) {
        const int band = rr[j] >> shift;
        const int pos = atomicAdd(&lcount[band], 1);
        if (pos < PAD_) {
            const unsigned int e = ((unsigned int)(rr[j] & rmask) << 28)
                                 | ((unsigned int)cc[j] << 16)
                                 | (unsigned int)f2bf(vv[j]);
            mbase[(band * 256 + chunk) * PAD_ + pos] = e;
        }
    }
    __syncthreads();
    cnt[(mat * 256 + t) * 256 + chunk] = lcount[t];
}

// ---------------------------------------------------------------- build
// One block == one band (16 up/gate rows or 4 down rows; 64KB fp32 LDS).
// Half 0 loads slots 0..15 UNCONDITIONALLY (one 64B line, 4 dwordx4; use
// guarded by count); half 1 walks the ~1e-6-rare >=16 tail. LDS fp32
// accumulate absorbs duplicates; streams bf16 rows out once.
__global__ __launch_bounds__(512) void build_kernel(
    const unsigned int* __restrict__ bands,
    const int* __restrict__ cnt,
    unsigned short* __restrict__ WUP,
    unsigned short* __restrict__ WGATE,
    unsigned short* __restrict__ WDOWN) {
    __shared__ float acc[16 * 1024];
    __shared__ int lcnt[256];
    const int b = blockIdx.x;
    const int t = threadIdx.x;
    const int mat = b >> 8;
    const int band = b & 255;
    unsigned int width;
    unsigned short* out;
    if (mat == 0)      { width = 1024; out = WUP + band * 16 * 1024; }
    else if (mat == 1) { width = 1024; out = WGATE + band * 16 * 1024; }
    else               { width = 4096; out = WDOWN + band * 4 * 4096; }

    for (int k = 0; k < 8; ++k)
        *(float4*)&acc[(k * 512 + t) * 4] = make_float4(0.f, 0.f, 0.f, 0.f);
    if (t < 256) lcnt[t] = cnt[(mat * 256 + band) * 256 + t];
    __syncthreads();

    const int chunk = t & 255;
    const int half = t >> 8;
    const unsigned int* seg = bands + (((mat * 256 + band) * 256) + chunk) * PAD_;
    const int c = lcnt[chunk];

    if (half == 0) {
        uint4 q[4];
        const uint4* sp = (const uint4*)seg;
        #pragma unroll
        for (int i = 0; i < 4; ++i) q[i] = sp[i];
        const unsigned int* qq = (const unsigned int*)q;
        #pragma unroll
        for (int j = 0; j < 16; ++j) {
            const unsigned int e = qq[j];
            if (j < c)
                atomicAdd(&acc[(e >> 28) * width + ((e >> 16) & 0xFFFu)],
                          __uint_as_float(e << 16));
        }
    } else {
        for (int j = 16; j < c && j < PAD_; ++j) {   // P ~ 1e-6 per chunk
            const unsigned int e = seg[j];
            atomicAdd(&acc[(e >> 28) * width + ((e >> 16) & 0xFFFu)],
                      __uint_as_float(e << 16));
        }
    }
    __syncthreads();

    for (int k = 0; k < 8; ++k) {
        const int cc = (k * 512 + t) * 4;
        ushort4 o;
        o.x = f2bf(acc[cc]);     o.y = f2bf(acc[cc + 1]);
        o.z = f2bf(acc[cc + 2]); o.w = f2bf(acc[cc + 3]);
        *(ushort4*)(out + cc) = o;
    }
}

// ---------------------------------------------------------------- up+gate GEMM
// BK=64 (two k-chunked 64x32 LDS sub-tiles), 16 MFMA per barrier pair.
// Tile 64Mx64N, wave-tile 32x32, dual acc, grid 512 = 2 blocks/CU.
__global__ __launch_bounds__(256) void gemm_upgate_kernel(
    const unsigned short* __restrict__ xb,      // [512][1024]
    const unsigned short* __restrict__ wup,     // [4096][1024]
    const unsigned short* __restrict__ wgate,   // [4096][1024]
    const float* __restrict__ up_bias,
    const float* __restrict__ gate_bias,
    unsigned short* __restrict__ hid) {         // [512][4096]
    __shared__ unsigned short sA[2 * 64 * 32];
    __shared__ unsigned short sBu[2 * 64 * 32];
    __shared__ unsigned short sBg[2 * 64 * 32];
    const int t = threadIdx.x;
    const int n0 = blockIdx.x * 64;
    const int m0 = blockIdx.y * 64;
    const int w = t >> 6, l = t & 63;
    const int wm = (w >> 1) * 32, wn = (w & 1) * 32;
    const int lr = l & 15, lkq = (l >> 4);

    float4v au[2][2], ag[2][2];
    for (int im = 0; im < 2; ++im)
        for (int in = 0; in < 2; ++in) {
            au[im][in] = float4v{0.f, 0.f, 0.f, 0.f};
            ag[im][in] = float4v{0.f, 0.f, 0.f, 0.f};
        }

    const int srow = t >> 2, scol = (t & 3) * 8;
    const unsigned short* gA  = xb    + (m0 + srow) * DIM_ + scol;
    const unsigned short* gBu = wup   + (n0 + srow) * DIM_ + scol;
    const unsigned short* gBg = wgate + (n0 + srow) * DIM_ + scol;

    for (int k0 = 0; k0 < DIM_; k0 += 64) {
        async16(gA + k0,       &sA[t * 8]);
        async16(gA + k0 + 32,  &sA[2048 + t * 8]);
        async16(gBu + k0,      &sBu[t * 8]);
        async16(gBu + k0 + 32, &sBu[2048 + t * 8]);
        async16(gBg + k0,      &sBg[t * 8]);
        async16(gBg + k0 + 32, &sBg[2048 + t * 8]);
        __syncthreads();
        #pragma unroll
        for (int kk = 0; kk < 2; ++kk) {
            const int kb = kk * 2048 + lkq * 8;
            short8 a[2], bu[2], bg[2];
            for (int im = 0; im < 2; ++im)
                a[im] = *(const short8*)&sA[kb + (wm + im * 16 + lr) * 32];
            for (int in = 0; in < 2; ++in) {
                bu[in] = *(const short8*)&sBu[kb + (wn + in * 16 + lr) * 32];
                bg[in] = *(const short8*)&sBg[kb + (wn + in * 16 + lr) * 32];
            }
            for (int im = 0; im < 2; ++im)
                for (int in = 0; in < 2; ++in) {
                    au[im][in] = __builtin_amdgcn_mfma_f32_16x16x32_bf16(
                        a[im], bu[in], au[im][in], 0, 0, 0);
                    ag[im][in] = __builtin_amdgcn_mfma_f32_16x16x32_bf16(
                        a[im], bg[in], ag[im][in], 0, 0, 0);
                }
        }
        __syncthreads();
    }

    for (int im = 0; im < 2; ++im) {
        for (int in = 0; in < 2; ++in) {
            const int n = n0 + wn + in * 16 + lr;
            const float ub = up_bias[n], gb = gate_bias[n];
            for (int r = 0; r < 4; ++r) {
                const int m = m0 + wm + im * 16 + lkq * 4 + r;
                const float u = au[im][in][r] + ub;
                const float g = ag[im][in][r] + gb;
                const float h = (u / (1.f + __expf(-u))) * g;
                hid[m * HIDDEN_ + n] = f2bf(h);
            }
        }
    }
}

// ---------------------------------------------------------------- down GEMM
// BK=64, split-K=8 (grid 1024 = 4 blocks/CU). atomicAdd epilogue onto
// d_out (pre-initialized to x + down_bias by prep role of bin_prep).
__global__ __launch_bounds__(256) void gemm_down_kernel(
    const unsigned short* __restrict__ hid,     // [512][4096]
    const unsigned short* __restrict__ wdown,   // [1024][4096]
    float* __restrict__ out) {                  // [512][1024]
    __shared__ unsigned short sA[2 * 64 * 32];
    __shared__ unsigned short sB[2 * 64 * 32];
    const int t = threadIdx.x;
    const int n0 = blockIdx.x * 64;
    const int m0 = blockIdx.y * 64;
    const int kb0 = blockIdx.z * 512;
    const int w = t >> 6, l = t & 63;
    const int wm = (w >> 1) * 32, wn = (w & 1) * 32;
    const int lr = l & 15, lkq = (l >> 4);

    float4v acc[2][2];
    for (int im = 0; im < 2; ++im)
        for (int in = 0; in < 2; ++in)
            acc[im][in] = float4v{0.f, 0.f, 0.f, 0.f};

    const int srow = t >> 2, scol = (t & 3) * 8;
    const unsigned short* gA = hid   + (m0 + srow) * HIDDEN_ + scol;
    const unsigned short* gB = wdown + (n0 + srow) * HIDDEN_ + scol;

    for (int k0 = kb0; k0 < kb0 + 512; k0 += 64) {
        async16(gA + k0,      &sA[t * 8]);
        async16(gA + k0 + 32, &sA[2048 + t * 8]);
        async16(gB + k0,      &sB[t * 8]);
        async16(gB + k0 + 32, &sB[2048 + t * 8]);
        __syncthreads();
        #pragma unroll
        for (int kk = 0; kk < 2; ++kk) {
            const int kb = kk * 2048 + lkq * 8;
            short8 a[2], b[2];
            for (int im = 0; im < 2; ++im)
                a[im] = *(const short8*)&sA[kb + (wm + im * 16 + lr) * 32];
            for (int in = 0; in < 2; ++in)
                b[in] = *(const short8*)&sB[kb + (wn + in * 16 + lr) * 32];
            for (int im = 0; im < 2; ++im)
                for (int in = 0; in < 2; ++in)
                    acc[im][in] = __builtin_amdgcn_mfma_f32_16x16x32_bf16(
                        a[im], b[in], acc[im][in], 0, 0, 0);
        }
        __syncthreads();
    }

    for (int im = 0; im < 2; ++im) {
        for (int in = 0; in < 2; ++in) {
            const int n = n0 + wn + in * 16 + lr;
            for (int r = 0; r < 4; ++r) {
                const int m = m0 + wm + im * 16 + lkq * 4 + r;
                atomicAdd(out + m * DIM_ + n, acc[im][in][r]);
            }
        }
    }
}

// ---------------------------------------------------------------- launch
extern "C" void kernel_launch(void* const* d_in, const int* in_sizes, int n_in,
                              void* d_out, int out_size, void* d_ws, size_t ws_size,
                              hipStream_t stream) {
    const float* x         = (const float*)d_in[0];
    const int*   up_row    = (const int*)d_in[1];
    const int*   up_col    = (const int*)d_in[2];
    const float* up_val    = (const float*)d_in[3];
    const float* up_bias   = (const float*)d_in[4];
    const int*   gate_row  = (const int*)d_in[5];
    const int*   gate_col  = (const int*)d_in[6];
    const float* gate_val  = (const float*)d_in[7];
    const float* gate_bias = (const float*)d_in[8];
    const int*   down_row  = (const int*)d_in[9];
    const int*   down_col  = (const int*)d_in[10];
    const float* down_val  = (const float*)d_in[11];
    const float* down_bias = (const float*)d_in[12];
    float* out = (float*)d_out;

    unsigned char* ws = (unsigned char*)d_ws;
    unsigned short* WUP   = (unsigned short*)(ws);
    unsigned short* WGATE = (unsigned short*)(ws + (8u << 20));
    unsigned short* WDOWN = (unsigned short*)(ws + (16u << 20));
    unsigned short* XB    = (unsigned short*)(ws + (24u << 20));
    unsigned short* HID   = (unsigned short*)(ws + (25u << 20));
    unsigned int*   BANDS = (unsigned int*)(ws + (29u << 20));
    int*            CNT   = (int*)(ws + (66u << 20));

    bin_prep_kernel<<<1024, 256, 0, stream>>>(
        up_row, up_col, up_val, gate_row, gate_col, gate_val,
        down_row, down_col, down_val, x, down_bias, BANDS, CNT, XB, out);

    build_kernel<<<768, 512, 0, stream>>>(BANDS, CNT, WUP, WGATE, WDOWN);

    gemm_upgate_kernel<<<dim3(HIDDEN_ / 64, TTOK_ / 64), 256, 0, stream>>>(
        XB, WUP, WGATE, up_bias, gate_bias, HID);

    gemm_down_kernel<<<dim3(DIM_ / 64, TTOK_ / 64, 8), 256, 0, stream>>>(
        HID, WDOWN, out);
}

// Round 12
// 136.349 us; speedup vs baseline: 1.0750x; 1.0231x over previous
//
#include <hip/hip_runtime.h>
#include <hip/hip_bf16.h>
#include <stdint.h>

// SparseSwiGLU on MI355X: fine-band radix densify -> bf16 weights -> MFMA GEMMs.
// R12 = R11 + LDS-staged coalesced bin writeout (48B segment bursts, global
// overflow list) + gemm_down split-K back to 4 (keep BK=64).
// T=512 tokens, DIM=1024, HIDDEN=4096, NNZ=262144 per matrix.
//
// Workspace layout (<= 68 MB):
//   [0,    8MB)  WUP    bf16 [4096][1024]   (B^T, K-contiguous)
//   [8MB, 16MB)  WGATE  bf16 [4096][1024]
//   [16MB,24MB)  WDOWN  bf16 [1024][4096]
//   [24MB,25MB)  XB     bf16 [512][1024]
//   [25MB,29MB)  HID    bf16 [512][4096]
//   [29MB,+9MB)  BANDS  uint[3][256 band][256 chunk][12 slot]
//   [66MB,+768K) CNT    int[3][256][256]
//   [67MB,+12B)  GOC    int[3]              overflow counters
//   [67MB+64,..) GOF    uint2[3][4096]      overflow entries (band, packed)

#define DIM_    1024
#define HIDDEN_ 4096
#define NNZ_    262144
#define TTOK_   512
#define PADL_   12              // 48 B segments; P(X>12|lam=4) ~ 2.7e-4

typedef __attribute__((ext_vector_type(8))) short short8;
typedef __attribute__((ext_vector_type(4))) float float4v;

__device__ inline unsigned short f2bf(float f) {
    union { float f; unsigned int u; } c; c.f = f;
    unsigned int u = c.u;
    unsigned int r = u + 0x7fffu + ((u >> 16) & 1u);   // RNE
    return (unsigned short)(r >> 16);
}

__device__ inline void async16(const unsigned short* g, unsigned short* l) {
    __builtin_amdgcn_global_load_lds(
        (const __attribute__((address_space(1))) unsigned int*)g,
        (__attribute__((address_space(3))) unsigned int*)l, 16, 0, 0);
}

// ---------------------------------------------------------------- bin+prep
// Blocks [0,768): bin — block = (mat, chunk of 1024 nnz), 256 bands/mat
//   (16 rows up/gate, 4 down). Entries staged in LDS stage[256][12], then
//   streamed out as 48B bursts (3 dwordx4/thread). Overflow -> global list.
// Blocks [768,1024): prep — x->bf16 and out = x + down_bias (4 float4/thr).
#define XC_ ((TTOK_ * DIM_) / 4)           // 131072 float4 units

__global__ __launch_bounds__(256) void bin_prep_kernel(
    const int* __restrict__ ur, const int* __restrict__ uc, const float* __restrict__ uv,
    const int* __restrict__ gr, const int* __restrict__ gc, const float* __restrict__ gv,
    const int* __restrict__ dr, const int* __restrict__ dc, const float* __restrict__ dv,
    const float* __restrict__ x, const float* __restrict__ down_bias,
    unsigned int* __restrict__ bands, int* __restrict__ cnt,
    int* __restrict__ goc, uint2* __restrict__ gof,
    unsigned short* __restrict__ xb, float* __restrict__ out) {
    const int b = blockIdx.x;
    const int t = threadIdx.x;
    if (b >= 768) {
        const unsigned int u0 = (b - 768) * 1024 + t * 4;
        #pragma unroll
        for (int q = 0; q < 4; ++q) {
            const unsigned int id = u0 + q;
            if (id < XC_) {
                float4 v = ((const float4*)x)[id];
                ushort4 o;
                o.x = f2bf(v.x); o.y = f2bf(v.y); o.z = f2bf(v.z); o.w = f2bf(v.w);
                ((ushort4*)xb)[id] = o;
            } else {
                const unsigned int i = id - XC_;
                float4 v = ((const float4*)x)[i];
                const int d = (i * 4) & (DIM_ - 1);
                const float4 bb = *(const float4*)(down_bias + d);
                float4 o;
                o.x = v.x + bb.x; o.y = v.y + bb.y; o.z = v.z + bb.z; o.w = v.w + bb.w;
                ((float4*)out)[i] = o;
            }
        }
        return;
    }
    __shared__ unsigned int stage[256][PADL_];   // 12 KB
    __shared__ int lcount[256];
    const int mat = b >> 8;          // 0 up, 1 gate, 2 down
    const int chunk = b & 255;
    const int*   rs = (mat == 0) ? ur : (mat == 1) ? gr : dr;
    const int*   cs = (mat == 0) ? uc : (mat == 1) ? gc : dc;
    const float* vs = (mat == 0) ? uv : (mat == 1) ? gv : dv;
    const int shift = (mat == 2) ? 2 : 4;   // rows/band: 4 (down), 16 (up/gate)
    const int rmask = (mat == 2) ? 3 : 15;
    lcount[t] = 0;
    __syncthreads();

    const int base = chunk * 1024 + t * 4;
    int4   r4 = *(const int4*)(rs + base);
    int4   c4 = *(const int4*)(cs + base);
    float4 v4 = *(const float4*)(vs + base);
    int   rr[4] = {r4.x, r4.y, r4.z, r4.w};
    int   cc[4] = {c4.x, c4.y, c4.z, c4.w};
    float vv[4] = {v4.x, v4.y, v4.z, v4.w};
    #pragma unroll
    for (int j = 0; j < 4; ++j) {
        const int band = rr[j] >> shift;
        const unsigned int e = ((unsigned int)(rr[j] & rmask) << 28)
                             | ((unsigned int)cc[j] << 16)
                             | (unsigned int)f2bf(vv[j]);
        const int pos = atomicAdd(&lcount[band], 1);
        if (pos < PADL_) {
            stage[band][pos] = e;
        } else {                       // ~53 grid-wide: global overflow list
            const int op = atomicAdd(&goc[mat], 1);
            gof[mat * 4096 + op] = make_uint2((unsigned int)band, e);
        }
    }
    __syncthreads();
    // coalesced writeout: thread t streams band t's 48B segment (3 dwordx4)
    unsigned int* seg = bands + ((unsigned int)(mat * 256 + t) * 256 + chunk) * PADL_;
    const uint4* sp = (const uint4*)&stage[t][0];
    *(uint4*)(seg)     = sp[0];
    *(uint4*)(seg + 4) = sp[1];
    *(uint4*)(seg + 8) = sp[2];
    cnt[(mat * 256 + t) * 256 + chunk] = lcount[t];
}

// ---------------------------------------------------------------- build
// One block == one band (16 up/gate rows or 4 down rows; 64KB fp32 LDS).
// Half 0 loads its chunk's 12 slots UNCONDITIONALLY (3 dwordx4; use guarded
// by count); half 1 scans the tiny global overflow list. Streams bf16 rows.
__global__ __launch_bounds__(512) void build_kernel(
    const unsigned int* __restrict__ bands,
    const int* __restrict__ cnt,
    const int* __restrict__ goc, const uint2* __restrict__ gof,
    unsigned short* __restrict__ WUP,
    unsigned short* __restrict__ WGATE,
    unsigned short* __restrict__ WDOWN) {
    __shared__ float acc[16 * 1024];
    __shared__ int lcnt[256];
    const int b = blockIdx.x;
    const int t = threadIdx.x;
    const int mat = b >> 8;
    const int band = b & 255;
    unsigned int width;
    unsigned short* out;
    if (mat == 0)      { width = 1024; out = WUP + band * 16 * 1024; }
    else if (mat == 1) { width = 1024; out = WGATE + band * 16 * 1024; }
    else               { width = 4096; out = WDOWN + band * 4 * 4096; }

    for (int k = 0; k < 8; ++k)
        *(float4*)&acc[(k * 512 + t) * 4] = make_float4(0.f, 0.f, 0.f, 0.f);
    if (t < 256) lcnt[t] = cnt[(mat * 256 + band) * 256 + t];
    __syncthreads();

    const int chunk = t & 255;
    const int half = t >> 8;
    const unsigned int* seg = bands + ((unsigned int)(mat * 256 + band) * 256 + chunk) * PADL_;
    const int c = lcnt[chunk];

    if (half == 0) {
        uint4 q[3];
        const uint4* sp = (const uint4*)seg;
        #pragma unroll
        for (int i = 0; i < 3; ++i) q[i] = sp[i];
        const unsigned int* qq = (const unsigned int*)q;
        #pragma unroll
        for (int j = 0; j < PADL_; ++j) {
            const unsigned int e = qq[j];
            if (j < c)
                atomicAdd(&acc[(e >> 28) * width + ((e >> 16) & 0xFFFu)],
                          __uint_as_float(e << 16));
        }
    } else {
        // overflow entries for this matrix (mean ~18/matrix): filter by band
        const int oc = goc[mat] < 4096 ? goc[mat] : 4096;
        for (int i = chunk; i < oc; i += 256) {
            uint2 oe = gof[mat * 4096 + i];
            if ((int)oe.x == band) {
                const unsigned int e = oe.y;
                atomicAdd(&acc[(e >> 28) * width + ((e >> 16) & 0xFFFu)],
                          __uint_as_float(e << 16));
            }
        }
    }
    __syncthreads();

    for (int k = 0; k < 8; ++k) {
        const int cc = (k * 512 + t) * 4;
        ushort4 o;
        o.x = f2bf(acc[cc]);     o.y = f2bf(acc[cc + 1]);
        o.z = f2bf(acc[cc + 2]); o.w = f2bf(acc[cc + 3]);
        *(ushort4*)(out + cc) = o;
    }
}

// ---------------------------------------------------------------- up+gate GEMM
// BK=64 (two k-chunked 64x32 LDS sub-tiles), 16 MFMA per barrier pair.
// Tile 64Mx64N, wave-tile 32x32, dual acc, grid 512 = 2 blocks/CU.
__global__ __launch_bounds__(256) void gemm_upgate_kernel(
    const unsigned short* __restrict__ xb,      // [512][1024]
    const unsigned short* __restrict__ wup,     // [4096][1024]
    const unsigned short* __restrict__ wgate,   // [4096][1024]
    const float* __restrict__ up_bias,
    const float* __restrict__ gate_bias,
    unsigned short* __restrict__ hid) {         // [512][4096]
    __shared__ unsigned short sA[2 * 64 * 32];
    __shared__ unsigned short sBu[2 * 64 * 32];
    __shared__ unsigned short sBg[2 * 64 * 32];
    const int t = threadIdx.x;
    const int n0 = blockIdx.x * 64;
    const int m0 = blockIdx.y * 64;
    const int w = t >> 6, l = t & 63;
    const int wm = (w >> 1) * 32, wn = (w & 1) * 32;
    const int lr = l & 15, lkq = (l >> 4);

    float4v au[2][2], ag[2][2];
    for (int im = 0; im < 2; ++im)
        for (int in = 0; in < 2; ++in) {
            au[im][in] = float4v{0.f, 0.f, 0.f, 0.f};
            ag[im][in] = float4v{0.f, 0.f, 0.f, 0.f};
        }

    const int srow = t >> 2, scol = (t & 3) * 8;
    const unsigned short* gA  = xb    + (m0 + srow) * DIM_ + scol;
    const unsigned short* gBu = wup   + (n0 + srow) * DIM_ + scol;
    const unsigned short* gBg = wgate + (n0 + srow) * DIM_ + scol;

    for (int k0 = 0; k0 < DIM_; k0 += 64) {
        async16(gA + k0,       &sA[t * 8]);
        async16(gA + k0 + 32,  &sA[2048 + t * 8]);
        async16(gBu + k0,      &sBu[t * 8]);
        async16(gBu + k0 + 32, &sBu[2048 + t * 8]);
        async16(gBg + k0,      &sBg[t * 8]);
        async16(gBg + k0 + 32, &sBg[2048 + t * 8]);
        __syncthreads();
        #pragma unroll
        for (int kk = 0; kk < 2; ++kk) {
            const int kb = kk * 2048 + lkq * 8;
            short8 a[2], bu[2], bg[2];
            for (int im = 0; im < 2; ++im)
                a[im] = *(const short8*)&sA[kb + (wm + im * 16 + lr) * 32];
            for (int in = 0; in < 2; ++in) {
                bu[in] = *(const short8*)&sBu[kb + (wn + in * 16 + lr) * 32];
                bg[in] = *(const short8*)&sBg[kb + (wn + in * 16 + lr) * 32];
            }
            for (int im = 0; im < 2; ++im)
                for (int in = 0; in < 2; ++in) {
                    au[im][in] = __builtin_amdgcn_mfma_f32_16x16x32_bf16(
                        a[im], bu[in], au[im][in], 0, 0, 0);
                    ag[im][in] = __builtin_amdgcn_mfma_f32_16x16x32_bf16(
                        a[im], bg[in], ag[im][in], 0, 0, 0);
                }
        }
        __syncthreads();
    }

    for (int im = 0; im < 2; ++im) {
        for (int in = 0; in < 2; ++in) {
            const int n = n0 + wn + in * 16 + lr;
            const float ub = up_bias[n], gb = gate_bias[n];
            for (int r = 0; r < 4; ++r) {
                const int m = m0 + wm + im * 16 + lkq * 4 + r;
                const float u = au[im][in][r] + ub;
                const float g = ag[im][in][r] + gb;
                const float h = (u / (1.f + __expf(-u))) * g;
                hid[m * HIDDEN_ + n] = f2bf(h);
            }
        }
    }
}

// ---------------------------------------------------------------- down GEMM
// BK=64, split-K=4 (grid 512 = 2 blocks/CU; halves d_out atomic traffic
// vs split-K=8). atomicAdd epilogue onto d_out (pre-init x + down_bias).
__global__ __launch_bounds__(256) void gemm_down_kernel(
    const unsigned short* __restrict__ hid,     // [512][4096]
    const unsigned short* __restrict__ wdown,   // [1024][4096]
    float* __restrict__ out) {                  // [512][1024]
    __shared__ unsigned short sA[2 * 64 * 32];
    __shared__ unsigned short sB[2 * 64 * 32];
    const int t = threadIdx.x;
    const int n0 = blockIdx.x * 64;
    const int m0 = blockIdx.y * 64;
    const int kb0 = blockIdx.z * 1024;
    const int w = t >> 6, l = t & 63;
    const int wm = (w >> 1) * 32, wn = (w & 1) * 32;
    const int lr = l & 15, lkq = (l >> 4);

    float4v acc[2][2];
    for (int im = 0; im < 2; ++im)
        for (int in = 0; in < 2; ++in)
            acc[im][in] = float4v{0.f, 0.f, 0.f, 0.f};

    const int srow = t >> 2, scol = (t & 3) * 8;
    const unsigned short* gA = hid   + (m0 + srow) * HIDDEN_ + scol;
    const unsigned short* gB = wdown + (n0 + srow) * HIDDEN_ + scol;

    for (int k0 = kb0; k0 < kb0 + 1024; k0 += 64) {
        async16(gA + k0,      &sA[t * 8]);
        async16(gA + k0 + 32, &sA[2048 + t * 8]);
        async16(gB + k0,      &sB[t * 8]);
        async16(gB + k0 + 32, &sB[2048 + t * 8]);
        __syncthreads();
        #pragma unroll
        for (int kk = 0; kk < 2; ++kk) {
            const int kb = kk * 2048 + lkq * 8;
            short8 a[2], b[2];
            for (int im = 0; im < 2; ++im)
                a[im] = *(const short8*)&sA[kb + (wm + im * 16 + lr) * 32];
            for (int in = 0; in < 2; ++in)
                b[in] = *(const short8*)&sB[kb + (wn + in * 16 + lr) * 32];
            for (int im = 0; im < 2; ++im)
                for (int in = 0; in < 2; ++in)
                    acc[im][in] = __builtin_amdgcn_mfma_f32_16x16x32_bf16(
                        a[im], b[in], acc[im][in], 0, 0, 0);
        }
        __syncthreads();
    }

    for (int im = 0; im < 2; ++im) {
        for (int in = 0; in < 2; ++in) {
            const int n = n0 + wn + in * 16 + lr;
            for (int r = 0; r < 4; ++r) {
                const int m = m0 + wm + im * 16 + lkq * 4 + r;
                atomicAdd(out + m * DIM_ + n, acc[im][in][r]);
            }
        }
    }
}

// ---------------------------------------------------------------- launch
extern "C" void kernel_launch(void* const* d_in, const int* in_sizes, int n_in,
                              void* d_out, int out_size, void* d_ws, size_t ws_size,
                              hipStream_t stream) {
    const float* x         = (const float*)d_in[0];
    const int*   up_row    = (const int*)d_in[1];
    const int*   up_col    = (const int*)d_in[2];
    const float* up_val    = (const float*)d_in[3];
    const float* up_bias   = (const float*)d_in[4];
    const int*   gate_row  = (const int*)d_in[5];
    const int*   gate_col  = (const int*)d_in[6];
    const float* gate_val  = (const float*)d_in[7];
    const float* gate_bias = (const float*)d_in[8];
    const int*   down_row  = (const int*)d_in[9];
    const int*   down_col  = (const int*)d_in[10];
    const float* down_val  = (const float*)d_in[11];
    const float* down_bias = (const float*)d_in[12];
    float* out = (float*)d_out;

    unsigned char* ws = (unsigned char*)d_ws;
    unsigned short* WUP   = (unsigned short*)(ws);
    unsigned short* WGATE = (unsigned short*)(ws + (8u << 20));
    unsigned short* WDOWN = (unsigned short*)(ws + (16u << 20));
    unsigned short* XB    = (unsigned short*)(ws + (24u << 20));
    unsigned short* HID   = (unsigned short*)(ws + (25u << 20));
    unsigned int*   BANDS = (unsigned int*)(ws + (29u << 20));
    int*            CNT   = (int*)(ws + (66u << 20));
    int*            GOC   = (int*)(ws + (67u << 20));
    uint2*          GOF   = (uint2*)(ws + (67u << 20) + 64);

    hipMemsetAsync(GOC, 0, 3 * sizeof(int), stream);

    bin_prep_kernel<<<1024, 256, 0, stream>>>(
        up_row, up_col, up_val, gate_row, gate_col, gate_val,
        down_row, down_col, down_val, x, down_bias, BANDS, CNT, GOC, GOF, XB, out);

    build_kernel<<<768, 512, 0, stream>>>(BANDS, CNT, GOC, GOF, WUP, WGATE, WDOWN);

    gemm_upgate_kernel<<<dim3(HIDDEN_ / 64, TTOK_ / 64), 256, 0, stream>>>(
        XB, WUP, WGATE, up_bias, gate_bias, HID);

    gemm_down_kernel<<<dim3(DIM_ / 64, TTOK_ / 64, 4), 256, 0, stream>>>(
        HID, WDOWN, out);
}

// Round 13
// 135.248 us; speedup vs baseline: 1.0837x; 1.0081x over previous
//
#include <hip/hip_runtime.h>
#include <hip/hip_bf16.h>
#include <stdint.h>

// SparseSwiGLU on MI355X: fine-band radix densify -> bf16 weights -> MFMA GEMMs.
// R13 = R12 + split-band build: each 16-row band built by TWO blocks (8 rows
// each; 32KB LDS -> 4 blocks/CU, full wave occupancy), bin side unchanged.
// T=512 tokens, DIM=1024, HIDDEN=4096, NNZ=262144 per matrix.
//
// Workspace layout (<= 68 MB):
//   [0,    8MB)  WUP    bf16 [4096][1024]   (B^T, K-contiguous)
//   [8MB, 16MB)  WGATE  bf16 [4096][1024]
//   [16MB,24MB)  WDOWN  bf16 [1024][4096]
//   [24MB,25MB)  XB     bf16 [512][1024]
//   [25MB,29MB)  HID    bf16 [512][4096]
//   [29MB,+9MB)  BANDS  uint[3][256 band][256 chunk][12 slot]
//   [66MB,+768K) CNT    int[3][256][256]
//   [67MB,+12B)  GOC    int[3]              overflow counters
//   [67MB+64,..) GOF    uint2[3][4096]      overflow entries (band, packed)

#define DIM_    1024
#define HIDDEN_ 4096
#define NNZ_    262144
#define TTOK_   512
#define PADL_   12              // 48 B segments; P(X>12|lam=4) ~ 2.7e-4

typedef __attribute__((ext_vector_type(8))) short short8;
typedef __attribute__((ext_vector_type(4))) float float4v;

__device__ inline unsigned short f2bf(float f) {
    union { float f; unsigned int u; } c; c.f = f;
    unsigned int u = c.u;
    unsigned int r = u + 0x7fffu + ((u >> 16) & 1u);   // RNE
    return (unsigned short)(r >> 16);
}

__device__ inline void async16(const unsigned short* g, unsigned short* l) {
    __builtin_amdgcn_global_load_lds(
        (const __attribute__((address_space(1))) unsigned int*)g,
        (__attribute__((address_space(3))) unsigned int*)l, 16, 0, 0);
}

// ---------------------------------------------------------------- bin+prep (R12)
// Blocks [0,768): bin — block = (mat, chunk of 1024 nnz), 256 bands/mat
//   (16 rows up/gate, 4 down). Entries staged in LDS stage[256][12], then
//   streamed out as 48B bursts (3 dwordx4/thread). Overflow -> global list.
// Blocks [768,1024): prep — x->bf16 and out = x + down_bias (4 float4/thr).
#define XC_ ((TTOK_ * DIM_) / 4)           // 131072 float4 units

__global__ __launch_bounds__(256) void bin_prep_kernel(
    const int* __restrict__ ur, const int* __restrict__ uc, const float* __restrict__ uv,
    const int* __restrict__ gr, const int* __restrict__ gc, const float* __restrict__ gv,
    const int* __restrict__ dr, const int* __restrict__ dc, const float* __restrict__ dv,
    const float* __restrict__ x, const float* __restrict__ down_bias,
    unsigned int* __restrict__ bands, int* __restrict__ cnt,
    int* __restrict__ goc, uint2* __restrict__ gof,
    unsigned short* __restrict__ xb, float* __restrict__ out) {
    const int b = blockIdx.x;
    const int t = threadIdx.x;
    if (b >= 768) {
        const unsigned int u0 = (b - 768) * 1024 + t * 4;
        #pragma unroll
        for (int q = 0; q < 4; ++q) {
            const unsigned int id = u0 + q;
            if (id < XC_) {
                float4 v = ((const float4*)x)[id];
                ushort4 o;
                o.x = f2bf(v.x); o.y = f2bf(v.y); o.z = f2bf(v.z); o.w = f2bf(v.w);
                ((ushort4*)xb)[id] = o;
            } else {
                const unsigned int i = id - XC_;
                float4 v = ((const float4*)x)[i];
                const int d = (i * 4) & (DIM_ - 1);
                const float4 bb = *(const float4*)(down_bias + d);
                float4 o;
                o.x = v.x + bb.x; o.y = v.y + bb.y; o.z = v.z + bb.z; o.w = v.w + bb.w;
                ((float4*)out)[i] = o;
            }
        }
        return;
    }
    __shared__ unsigned int stage[256][PADL_];   // 12 KB
    __shared__ int lcount[256];
    const int mat = b >> 8;          // 0 up, 1 gate, 2 down
    const int chunk = b & 255;
    const int*   rs = (mat == 0) ? ur : (mat == 1) ? gr : dr;
    const int*   cs = (mat == 0) ? uc : (mat == 1) ? gc : dc;
    const float* vs = (mat == 0) ? uv : (mat == 1) ? gv : dv;
    const int shift = (mat == 2) ? 2 : 4;   // rows/band: 4 (down), 16 (up/gate)
    const int rmask = (mat == 2) ? 3 : 15;
    lcount[t] = 0;
    __syncthreads();

    const int base = chunk * 1024 + t * 4;
    int4   r4 = *(const int4*)(rs + base);
    int4   c4 = *(const int4*)(cs + base);
    float4 v4 = *(const float4*)(vs + base);
    int   rr[4] = {r4.x, r4.y, r4.z, r4.w};
    int   cc[4] = {c4.x, c4.y, c4.z, c4.w};
    float vv[4] = {v4.x, v4.y, v4.z, v4.w};
    #pragma unroll
    for (int j = 0; j < 4; ++j) {
        const int band = rr[j] >> shift;
        const unsigned int e = ((unsigned int)(rr[j] & rmask) << 28)
                             | ((unsigned int)cc[j] << 16)
                             | (unsigned int)f2bf(vv[j]);
        const int pos = atomicAdd(&lcount[band], 1);
        if (pos < PADL_) {
            stage[band][pos] = e;
        } else {                       // ~53 grid-wide: global overflow list
            const int op = atomicAdd(&goc[mat], 1);
            gof[mat * 4096 + op] = make_uint2((unsigned int)band, e);
        }
    }
    __syncthreads();
    // coalesced writeout: thread t streams band t's 48B segment (3 dwordx4)
    unsigned int* seg = bands + ((unsigned int)(mat * 256 + t) * 256 + chunk) * PADL_;
    const uint4* sp = (const uint4*)&stage[t][0];
    *(uint4*)(seg)     = sp[0];
    *(uint4*)(seg + 4) = sp[1];
    *(uint4*)(seg + 8) = sp[2];
    cnt[(mat * 256 + t) * 256 + chunk] = lcount[t];
}

// ---------------------------------------------------------------- build
// R13: TWO blocks per band, each owning half the rows (8 up/gate, 2 down);
// 32KB fp32 LDS + 1KB lcnt -> 4 blocks/CU (full 32 waves). Both halves scan
// the same 48B segments (2x L2-resident read amp) and filter entries by
// row-half. Half 0 threads: unconditional 3x dwordx4 slot load, guarded use;
// half 1 threads: scan tiny global overflow list. Streams bf16 rows out.
__global__ __launch_bounds__(512) void build_kernel(
    const unsigned int* __restrict__ bands,
    const int* __restrict__ cnt,
    const int* __restrict__ goc, const uint2* __restrict__ gof,
    unsigned short* __restrict__ WUP,
    unsigned short* __restrict__ WGATE,
    unsigned short* __restrict__ WDOWN) {
    __shared__ float acc[8 * 1024];
    __shared__ int lcnt[256];
    const int b = blockIdx.x;
    const int t = threadIdx.x;
    const int mat = b / 512;
    const int rem = b - mat * 512;
    const int band = rem >> 1;
    const int hb = rem & 1;            // row half within the band
    unsigned int width, rhalf;
    unsigned short* out;
    if (mat == 0)      { width = 1024; rhalf = 8; out = WUP + (band * 16 + hb * 8) * 1024; }
    else if (mat == 1) { width = 1024; rhalf = 8; out = WGATE + (band * 16 + hb * 8) * 1024; }
    else               { width = 4096; rhalf = 2; out = WDOWN + (band * 4 + hb * 2) * 4096; }
    const unsigned int rbase = hb * rhalf;

    for (int k = 0; k < 4; ++k)
        *(float4*)&acc[(k * 512 + t) * 4] = make_float4(0.f, 0.f, 0.f, 0.f);
    if (t < 256) lcnt[t] = cnt[(mat * 256 + band) * 256 + t];
    __syncthreads();

    const int chunk = t & 255;
    const int half = t >> 8;
    const unsigned int* seg = bands + ((unsigned int)(mat * 256 + band) * 256 + chunk) * PADL_;
    const int c = lcnt[chunk];

    if (half == 0) {
        uint4 q[3];
        const uint4* sp = (const uint4*)seg;
        #pragma unroll
        for (int i = 0; i < 3; ++i) q[i] = sp[i];
        const unsigned int* qq = (const unsigned int*)q;
        #pragma unroll
        for (int j = 0; j < PADL_; ++j) {
            const unsigned int e = qq[j];
            const unsigned int r2 = (e >> 28) - rbase;   // unsigned wrap filter
            if (j < c && r2 < rhalf)
                atomicAdd(&acc[r2 * width + ((e >> 16) & 0xFFFu)],
                          __uint_as_float(e << 16));
        }
    } else {
        // overflow entries for this matrix (mean ~18/matrix): filter by band+half
        const int oc = goc[mat] < 4096 ? goc[mat] : 4096;
        for (int i = chunk; i < oc; i += 256) {
            uint2 oe = gof[mat * 4096 + i];
            if ((int)oe.x == band) {
                const unsigned int e = oe.y;
                const unsigned int r2 = (e >> 28) - rbase;
                if (r2 < rhalf)
                    atomicAdd(&acc[r2 * width + ((e >> 16) & 0xFFFu)],
                              __uint_as_float(e << 16));
            }
        }
    }
    __syncthreads();

    for (int k = 0; k < 4; ++k) {
        const int cc = (k * 512 + t) * 4;
        ushort4 o;
        o.x = f2bf(acc[cc]);     o.y = f2bf(acc[cc + 1]);
        o.z = f2bf(acc[cc + 2]); o.w = f2bf(acc[cc + 3]);
        *(ushort4*)(out + cc) = o;
    }
}

// ---------------------------------------------------------------- up+gate GEMM
// BK=64 (two k-chunked 64x32 LDS sub-tiles), 16 MFMA per barrier pair.
// Tile 64Mx64N, wave-tile 32x32, dual acc, grid 512 = 2 blocks/CU.
__global__ __launch_bounds__(256) void gemm_upgate_kernel(
    const unsigned short* __restrict__ xb,      // [512][1024]
    const unsigned short* __restrict__ wup,     // [4096][1024]
    const unsigned short* __restrict__ wgate,   // [4096][1024]
    const float* __restrict__ up_bias,
    const float* __restrict__ gate_bias,
    unsigned short* __restrict__ hid) {         // [512][4096]
    __shared__ unsigned short sA[2 * 64 * 32];
    __shared__ unsigned short sBu[2 * 64 * 32];
    __shared__ unsigned short sBg[2 * 64 * 32];
    const int t = threadIdx.x;
    const int n0 = blockIdx.x * 64;
    const int m0 = blockIdx.y * 64;
    const int w = t >> 6, l = t & 63;
    const int wm = (w >> 1) * 32, wn = (w & 1) * 32;
    const int lr = l & 15, lkq = (l >> 4);

    float4v au[2][2], ag[2][2];
    for (int im = 0; im < 2; ++im)
        for (int in = 0; in < 2; ++in) {
            au[im][in] = float4v{0.f, 0.f, 0.f, 0.f};
            ag[im][in] = float4v{0.f, 0.f, 0.f, 0.f};
        }

    const int srow = t >> 2, scol = (t & 3) * 8;
    const unsigned short* gA  = xb    + (m0 + srow) * DIM_ + scol;
    const unsigned short* gBu = wup   + (n0 + srow) * DIM_ + scol;
    const unsigned short* gBg = wgate + (n0 + srow) * DIM_ + scol;

    for (int k0 = 0; k0 < DIM_; k0 += 64) {
        async16(gA + k0,       &sA[t * 8]);
        async16(gA + k0 + 32,  &sA[2048 + t * 8]);
        async16(gBu + k0,      &sBu[t * 8]);
        async16(gBu + k0 + 32, &sBu[2048 + t * 8]);
        async16(gBg + k0,      &sBg[t * 8]);
        async16(gBg + k0 + 32, &sBg[2048 + t * 8]);
        __syncthreads();
        #pragma unroll
        for (int kk = 0; kk < 2; ++kk) {
            const int kb = kk * 2048 + lkq * 8;
            short8 a[2], bu[2], bg[2];
            for (int im = 0; im < 2; ++im)
                a[im] = *(const short8*)&sA[kb + (wm + im * 16 + lr) * 32];
            for (int in = 0; in < 2; ++in) {
                bu[in] = *(const short8*)&sBu[kb + (wn + in * 16 + lr) * 32];
                bg[in] = *(const short8*)&sBg[kb + (wn + in * 16 + lr) * 32];
            }
            for (int im = 0; im < 2; ++im)
                for (int in = 0; in < 2; ++in) {
                    au[im][in] = __builtin_amdgcn_mfma_f32_16x16x32_bf16(
                        a[im], bu[in], au[im][in], 0, 0, 0);
                    ag[im][in] = __builtin_amdgcn_mfma_f32_16x16x32_bf16(
                        a[im], bg[in], ag[im][in], 0, 0, 0);
                }
        }
        __syncthreads();
    }

    for (int im = 0; im < 2; ++im) {
        for (int in = 0; in < 2; ++in) {
            const int n = n0 + wn + in * 16 + lr;
            const float ub = up_bias[n], gb = gate_bias[n];
            for (int r = 0; r < 4; ++r) {
                const int m = m0 + wm + im * 16 + lkq * 4 + r;
                const float u = au[im][in][r] + ub;
                const float g = ag[im][in][r] + gb;
                const float h = (u / (1.f + __expf(-u))) * g;
                hid[m * HIDDEN_ + n] = f2bf(h);
            }
        }
    }
}

// ---------------------------------------------------------------- down GEMM
// BK=64, split-K=4 (grid 512 = 2 blocks/CU). atomicAdd epilogue onto d_out
// (pre-initialized to x + down_bias by prep role of bin_prep).
__global__ __launch_bounds__(256) void gemm_down_kernel(
    const unsigned short* __restrict__ hid,     // [512][4096]
    const unsigned short* __restrict__ wdown,   // [1024][4096]
    float* __restrict__ out) {                  // [512][1024]
    __shared__ unsigned short sA[2 * 64 * 32];
    __shared__ unsigned short sB[2 * 64 * 32];
    const int t = threadIdx.x;
    const int n0 = blockIdx.x * 64;
    const int m0 = blockIdx.y * 64;
    const int kb0 = blockIdx.z * 1024;
    const int w = t >> 6, l = t & 63;
    const int wm = (w >> 1) * 32, wn = (w & 1) * 32;
    const int lr = l & 15, lkq = (l >> 4);

    float4v acc[2][2];
    for (int im = 0; im < 2; ++im)
        for (int in = 0; in < 2; ++in)
            acc[im][in] = float4v{0.f, 0.f, 0.f, 0.f};

    const int srow = t >> 2, scol = (t & 3) * 8;
    const unsigned short* gA = hid   + (m0 + srow) * HIDDEN_ + scol;
    const unsigned short* gB = wdown + (n0 + srow) * HIDDEN_ + scol;

    for (int k0 = kb0; k0 < kb0 + 1024; k0 += 64) {
        async16(gA + k0,      &sA[t * 8]);
        async16(gA + k0 + 32, &sA[2048 + t * 8]);
        async16(gB + k0,      &sB[t * 8]);
        async16(gB + k0 + 32, &sB[2048 + t * 8]);
        __syncthreads();
        #pragma unroll
        for (int kk = 0; kk < 2; ++kk) {
            const int kb = kk * 2048 + lkq * 8;
            short8 a[2], b[2];
            for (int im = 0; im < 2; ++im)
                a[im] = *(const short8*)&sA[kb + (wm + im * 16 + lr) * 32];
            for (int in = 0; in < 2; ++in)
                b[in] = *(const short8*)&sB[kb + (wn + in * 16 + lr) * 32];
            for (int im = 0; im < 2; ++im)
                for (int in = 0; in < 2; ++in)
                    acc[im][in] = __builtin_amdgcn_mfma_f32_16x16x32_bf16(
                        a[im], b[in], acc[im][in], 0, 0, 0);
        }
        __syncthreads();
    }

    for (int im = 0; im < 2; ++im) {
        for (int in = 0; in < 2; ++in) {
            const int n = n0 + wn + in * 16 + lr;
            for (int r = 0; r < 4; ++r) {
                const int m = m0 + wm + im * 16 + lkq * 4 + r;
                atomicAdd(out + m * DIM_ + n, acc[im][in][r]);
            }
        }
    }
}

// ---------------------------------------------------------------- launch
extern "C" void kernel_launch(void* const* d_in, const int* in_sizes, int n_in,
                              void* d_out, int out_size, void* d_ws, size_t ws_size,
                              hipStream_t stream) {
    const float* x         = (const float*)d_in[0];
    const int*   up_row    = (const int*)d_in[1];
    const int*   up_col    = (const int*)d_in[2];
    const float* up_val    = (const float*)d_in[3];
    const float* up_bias   = (const float*)d_in[4];
    const int*   gate_row  = (const int*)d_in[5];
    const int*   gate_col  = (const int*)d_in[6];
    const float* gate_val  = (const float*)d_in[7];
    const float* gate_bias = (const float*)d_in[8];
    const int*   down_row  = (const int*)d_in[9];
    const int*   down_col  = (const int*)d_in[10];
    const float* down_val  = (const float*)d_in[11];
    const float* down_bias = (const float*)d_in[12];
    float* out = (float*)d_out;

    unsigned char* ws = (unsigned char*)d_ws;
    unsigned short* WUP   = (unsigned short*)(ws);
    unsigned short* WGATE = (unsigned short*)(ws + (8u << 20));
    unsigned short* WDOWN = (unsigned short*)(ws + (16u << 20));
    unsigned short* XB    = (unsigned short*)(ws + (24u << 20));
    unsigned short* HID   = (unsigned short*)(ws + (25u << 20));
    unsigned int*   BANDS = (unsigned int*)(ws + (29u << 20));
    int*            CNT   = (int*)(ws + (66u << 20));
    int*            GOC   = (int*)(ws + (67u << 20));
    uint2*          GOF   = (uint2*)(ws + (67u << 20) + 64);

    hipMemsetAsync(GOC, 0, 3 * sizeof(int), stream);

    bin_prep_kernel<<<1024, 256, 0, stream>>>(
        up_row, up_col, up_val, gate_row, gate_col, gate_val,
        down_row, down_col, down_val, x, down_bias, BANDS, CNT, GOC, GOF, XB, out);

    build_kernel<<<1536, 512, 0, stream>>>(BANDS, CNT, GOC, GOF, WUP, WGATE, WDOWN);

    gemm_upgate_kernel<<<dim3(HIDDEN_ / 64, TTOK_ / 64), 256, 0, stream>>>(
        XB, WUP, WGATE, up_bias, gate_bias, HID);

    gemm_down_kernel<<<dim3(DIM_ / 64, TTOK_ / 64, 4), 256, 0, stream>>>(
        HID, WDOWN, out);
}